// Round 1
// baseline (761.791 us; speedup 1.0000x reference)
//
#include <hip/hip_runtime.h>

// BetaBernoulliMixture: per row r, per time t:
//   s_prev = #ones in obs[r, 0..t-1];  f_prev = t - s_prev
//   a1 = alpha1+s_prev, b1 = beta1+f_prev, a2 = alpha2+s_prev, b2 = beta2+f_prev
//   d(t) = sum_{u<t} [ log(sel2_u*(AB1+u)) - log(sel1_u*(AB2+u)) ]
//   post_mixweight = w / (w + (1-w)*exp(d))
// Output layout: [5, B, T] = {a1, b1, a2, b2, post_mixweight}
//
// R4 structure: ONE WAVE PER ROW (4 waves/block, 1024 blocks for B=4096).
// R3 (block-per-row) had 2 __syncthreads per 1024-el segment; hipcc drains
// vmcnt(0)/lgkmcnt(0) at every barrier, pulling the prefetch load (~900 cy)
// and the 5 NT-store drains into the critical path 16x/row -> ~330 us
// kernel vs ~130 us BW roofline. Wave-per-row needs NO barriers and NO LDS:
// carries live in registers, bit cumsum via __ballot+popc, delta cumsum via
// 6-step __shfl_up wave scan. 16 waves/CU resident (4096 rows / 256 CU),
// prefetch-by-1 gives the load a full iteration of cover, NT stores from
// multiple iterations stay in flight (6 VMEM ops/iter << vmcnt depth).

#define BLOCK 256
#define VEC 4
#define WPB 4   // waves per block

typedef float v4f __attribute__((ext_vector_type(4)));

__global__ __launch_bounds__(BLOCK) void bbm_kernel(
    const float* __restrict__ obs,
    const float* __restrict__ alpha1, const float* __restrict__ beta1,
    const float* __restrict__ alpha2, const float* __restrict__ beta2,
    const float* __restrict__ mixw,
    float* __restrict__ out,
    int T, size_t bt, int Bn)
{
    const int tid  = threadIdx.x;
    const int lane = tid & 63;
    const int wid  = tid >> 6;
    const int row  = blockIdx.x * WPB + wid;
    if (row >= Bn) return;   // wave-uniform exit

    const float A1 = alpha1[row], B1 = beta1[row];
    const float A2 = alpha2[row], B2 = beta2[row];
    const float w  = mixw[0];
    const float AB1 = A1 + B1, AB2 = A2 + B2;
    const float w2 = 1.0f - w;

    const float* __restrict__ orow = obs + (size_t)row * T;
    float* __restrict__ obase = out + (size_t)row * T;

    const unsigned long long lt_mask = ((unsigned long long)1 << lane) - 1ull;

    int   carry_s = 0;
    float carry_d = 0.0f;

    const int EPI   = 64 * VEC;     // 256 elements per wave-iteration
    const int iters = T / EPI;      // 32 for T=8192

    // preload first iteration (lane-contiguous float4)
    v4f cur = *(const v4f*)(orow + lane * VEC);

    for (int it = 0; it < iters; ++it) {
        const int t0 = it * EPI + lane * VEC;

        // prefetch next iteration's obs; consumed one full iteration later,
        // so its s_waitcnt lands after the scan chains (no barrier drains it)
        v4f nxt;
        if (it + 1 < iters) nxt = *(const v4f*)(orow + (it + 1) * EPI + lane * VEC);

        // ---- bits + thread-local exclusive prefix ----
        int bit[VEC], sloc[VEC];
        int ts = 0;
        #pragma unroll
        for (int j = 0; j < VEC; ++j) { bit[j] = cur[j] > 0.5f; sloc[j] = ts; ts += bit[j]; }

        // ---- wave bit scan via ballot+popc (short dependency chain) ----
        unsigned long long m0 = __ballot(bit[0]);
        unsigned long long m1 = __ballot(bit[1]);
        unsigned long long m2 = __ballot(bit[2]);
        unsigned long long m3 = __ballot(bit[3]);
        const int wave_excl = __builtin_popcountll(m0 & lt_mask)
                            + __builtin_popcountll(m1 & lt_mask)
                            + __builtin_popcountll(m2 & lt_mask)
                            + __builtin_popcountll(m3 & lt_mask);
        const int wave_tot  = __builtin_popcountll(m0) + __builtin_popcountll(m1)
                            + __builtin_popcountll(m2) + __builtin_popcountll(m3);
        const int tbase_s = carry_s + wave_excl;

        // ---- per-elem delta + thread-local exclusive prefix ----
        float dloc[VEC];
        float td = 0.0f;
        #pragma unroll
        for (int j = 0; j < VEC; ++j) {
            const float ft = (float)(t0 + j);
            const float fs = (float)(tbase_s + sloc[j]);
            const float fp = ft - fs;
            const float sel1 = bit[j] ? (A1 + fs) : (B1 + fp);
            const float sel2 = bit[j] ? (A2 + fs) : (B2 + fp);
            const float delta = __logf(sel2 * (AB1 + ft)) - __logf(sel1 * (AB2 + ft));
            dloc[j] = td;
            td += delta;
        }

        // ---- wave shuffle-scan over per-thread delta totals ----
        float incl_d = td;
        #pragma unroll
        for (int off = 1; off < 64; off <<= 1) {
            float n = __shfl_up(incl_d, off, 64);
            if (lane >= off) incl_d += n;
        }
        const float tbase_d = carry_d + (incl_d - td);   // exclusive prefix
        const float totald  = __shfl(incl_d, 63, 64);    // wave total

        // ---- outputs: one lane-contiguous float4 NT store per stream ----
        v4f va1, vb1, va2, vb2, vpm;
        #pragma unroll
        for (int j = 0; j < VEC; ++j) {
            const float ft = (float)(t0 + j);
            const float fs = (float)(tbase_s + sloc[j]);
            const float fp = ft - fs;
            const float d  = tbase_d + dloc[j];
            va1[j] = A1 + fs;
            vb1[j] = B1 + fp;
            va2[j] = A2 + fs;
            vb2[j] = B2 + fp;
            vpm[j] = __fdividef(w, w + w2 * __expf(d));
        }
        float* p = obase + t0;
        __builtin_nontemporal_store(va1, (v4f*)(p));
        __builtin_nontemporal_store(vb1, (v4f*)(p + bt));
        __builtin_nontemporal_store(va2, (v4f*)(p + 2 * bt));
        __builtin_nontemporal_store(vb2, (v4f*)(p + 3 * bt));
        __builtin_nontemporal_store(vpm, (v4f*)(p + 4 * bt));

        carry_s += wave_tot;
        carry_d += totald;
        cur = nxt;
    }
}

extern "C" void kernel_launch(void* const* d_in, const int* in_sizes, int n_in,
                              void* d_out, int out_size, void* d_ws, size_t ws_size,
                              hipStream_t stream) {
    const float* obs    = (const float*)d_in[0];
    const float* alpha1 = (const float*)d_in[1];
    const float* beta1  = (const float*)d_in[2];
    const float* alpha2 = (const float*)d_in[3];
    const float* beta2  = (const float*)d_in[4];
    const float* mixw   = (const float*)d_in[5];

    const int Bn = in_sizes[1];
    const int Tn = in_sizes[0] / Bn;
    const size_t bt = (size_t)Bn * (size_t)Tn;

    const int grid = (Bn + WPB - 1) / WPB;
    bbm_kernel<<<grid, BLOCK, 0, stream>>>(obs, alpha1, beta1, alpha2, beta2,
                                           mixw, (float*)d_out, Tn, bt, Bn);
}

// Round 2
// 740.001 us; speedup vs baseline: 1.0294x; 1.0294x over previous
//
#include <hip/hip_runtime.h>

// BetaBernoulliMixture: per row r, per time t:
//   s_prev = #ones in obs[r, 0..t-1];  f_prev = t - s_prev
//   a1 = alpha1+s_prev, b1 = beta1+f_prev, a2 = alpha2+s_prev, b2 = beta2+f_prev
//   d(t) = sum_{u<t} [ log(sel2_u*(AB1+u)) - log(sel1_u*(AB2+u)) ]
//   post_mixweight = w / (w + (1-w)*exp(d))
// Output layout: [5, B, T] = {a1, b1, a2, b2, post_mixweight}
//
// R5 theory: R3 (block/row, barriers) == R4 (wave/row, zero barriers) at
// ~330us kernel vs ~130us traffic roofline -> bottleneck is NOT sync, it's
// HBM row-buffer locality: 4096 concurrent rows x 6 streams = ~24k
// interleaved 1KB bursts at power-of-two strides thrash the DRAM row
// buffers (~2.4 TB/s vs 6.2 TB/s that the harness fill gets sweeping the
// same buffer contiguously).
// R5 structure: ONE 1024-THREAD BLOCK PER ROW (16 waves), launch_bounds
// (1024,4) -> 1 block/CU -> ~256 rows in flight (16x fewer than R4), and
// each segment reads/writes 16KB CONTIGUOUS per stream (16x larger bursts).
// Cross-wave combine via LDS partials + 2 barriers/segment (2 segments for
// T=8192) -- barriers proven cheap by R3==R4. Prefetch of the next segment
// is issued AFTER the combine barriers so no barrier drains an unconsumed
// load (the only barriers after the prefetch come after its consumption).

#define BLOCK 1024
#define VEC 4
#define NWAVES (BLOCK / 64)   // 16

typedef float v4f __attribute__((ext_vector_type(4)));

__global__ __launch_bounds__(BLOCK, 4) void bbm_kernel(
    const float* __restrict__ obs,
    const float* __restrict__ alpha1, const float* __restrict__ beta1,
    const float* __restrict__ alpha2, const float* __restrict__ beta2,
    const float* __restrict__ mixw,
    float* __restrict__ out,
    int T, size_t bt)
{
    const int row  = blockIdx.x;
    const int tid  = threadIdx.x;
    const int lane = tid & 63;
    const int wid  = tid >> 6;

    __shared__ int   sPart[NWAVES];
    __shared__ float dPart[NWAVES];

    const float A1 = alpha1[row], B1 = beta1[row];
    const float A2 = alpha2[row], B2 = beta2[row];
    const float w  = mixw[0];
    const float AB1 = A1 + B1, AB2 = A2 + B2;
    const float w2 = 1.0f - w;

    const float* __restrict__ orow = obs + (size_t)row * T;
    float* __restrict__ obase = out + (size_t)row * T;

    const unsigned long long lt_mask = ((unsigned long long)1 << lane) - 1ull;

    int   carry_s = 0;
    float carry_d = 0.0f;

    const int EPB  = BLOCK * VEC;       // 4096 elements per block-segment
    const int segs = T / EPB;           // 2 for T=8192

    // preload first segment (thread-contiguous float4 -> 16KB/block burst)
    v4f cur = *(const v4f*)(orow + tid * VEC);

    for (int seg = 0; seg < segs; ++seg) {
        const int t0 = seg * EPB + tid * VEC;

        // ---- bits + thread-local exclusive prefix ----
        int bit[VEC], sloc[VEC];
        int ts = 0;
        #pragma unroll
        for (int j = 0; j < VEC; ++j) { bit[j] = cur[j] > 0.5f; sloc[j] = ts; ts += bit[j]; }

        // ---- wave bit scan via ballot+popc ----
        unsigned long long m0 = __ballot(bit[0]);
        unsigned long long m1 = __ballot(bit[1]);
        unsigned long long m2 = __ballot(bit[2]);
        unsigned long long m3 = __ballot(bit[3]);
        const int wave_excl = __builtin_popcountll(m0 & lt_mask)
                            + __builtin_popcountll(m1 & lt_mask)
                            + __builtin_popcountll(m2 & lt_mask)
                            + __builtin_popcountll(m3 & lt_mask);
        const int wave_tot  = __builtin_popcountll(m0) + __builtin_popcountll(m1)
                            + __builtin_popcountll(m2) + __builtin_popcountll(m3);
        if (lane == 0) sPart[wid] = wave_tot;
        __syncthreads();
        int prior = 0, total = 0;
        #pragma unroll
        for (int wI = 0; wI < NWAVES; ++wI) {
            int p = sPart[wI];
            total += p;
            if (wI < wid) prior += p;
        }
        const int tbase_s = carry_s + prior + wave_excl;

        // ---- per-elem delta + thread-local exclusive prefix ----
        float dloc[VEC];
        float td = 0.0f;
        #pragma unroll
        for (int j = 0; j < VEC; ++j) {
            const float ft = (float)(t0 + j);
            const float fs = (float)(tbase_s + sloc[j]);
            const float fp = ft - fs;
            const float sel1 = bit[j] ? (A1 + fs) : (B1 + fp);
            const float sel2 = bit[j] ? (A2 + fs) : (B2 + fp);
            const float delta = __logf(sel2 * (AB1 + ft)) - __logf(sel1 * (AB2 + ft));
            dloc[j] = td;
            td += delta;
        }

        // ---- wave shuffle-scan over per-thread delta totals ----
        float incl_d = td;
        #pragma unroll
        for (int off = 1; off < 64; off <<= 1) {
            float n = __shfl_up(incl_d, off, 64);
            if (lane >= off) incl_d += n;
        }
        if (lane == 63) dPart[wid] = incl_d;
        __syncthreads();
        float priord = 0.0f, totald = 0.0f;
        #pragma unroll
        for (int wI = 0; wI < NWAVES; ++wI) {
            float p = dPart[wI];
            totald += p;
            if (wI < wid) priord += p;
        }
        const float tbase_d = carry_d + priord + (incl_d - td);

        // ---- prefetch next segment AFTER the barriers (no barrier between
        //      issue and consumption -> full-segment latency cover, no drain)
        v4f nxt;
        if (seg + 1 < segs) nxt = *(const v4f*)(orow + (seg + 1) * EPB + tid * VEC);

        // ---- outputs: one thread-contiguous float4 NT store per stream
        //      (block covers 16KB contiguous per stream) ----
        v4f va1, vb1, va2, vb2, vpm;
        #pragma unroll
        for (int j = 0; j < VEC; ++j) {
            const float ft = (float)(t0 + j);
            const float fs = (float)(tbase_s + sloc[j]);
            const float fp = ft - fs;
            const float d  = tbase_d + dloc[j];
            va1[j] = A1 + fs;
            vb1[j] = B1 + fp;
            va2[j] = A2 + fs;
            vb2[j] = B2 + fp;
            vpm[j] = __fdividef(w, w + w2 * __expf(d));
        }
        float* p = obase + t0;
        __builtin_nontemporal_store(va1, (v4f*)(p));
        __builtin_nontemporal_store(vb1, (v4f*)(p + bt));
        __builtin_nontemporal_store(va2, (v4f*)(p + 2 * bt));
        __builtin_nontemporal_store(vb2, (v4f*)(p + 3 * bt));
        __builtin_nontemporal_store(vpm, (v4f*)(p + 4 * bt));

        carry_s += total;
        carry_d += totald;
        cur = nxt;
    }
}

extern "C" void kernel_launch(void* const* d_in, const int* in_sizes, int n_in,
                              void* d_out, int out_size, void* d_ws, size_t ws_size,
                              hipStream_t stream) {
    const float* obs    = (const float*)d_in[0];
    const float* alpha1 = (const float*)d_in[1];
    const float* beta1  = (const float*)d_in[2];
    const float* alpha2 = (const float*)d_in[3];
    const float* beta2  = (const float*)d_in[4];
    const float* mixw   = (const float*)d_in[5];

    const int Bn = in_sizes[1];
    const int Tn = in_sizes[0] / Bn;
    const size_t bt = (size_t)Bn * (size_t)Tn;

    bbm_kernel<<<Bn, BLOCK, 0, stream>>>(obs, alpha1, beta1, alpha2, beta2,
                                         mixw, (float*)d_out, Tn, bt);
}

// Round 3
// 737.882 us; speedup vs baseline: 1.0324x; 1.0029x over previous
//
#include <hip/hip_runtime.h>

// BetaBernoulliMixture: per row r, per time t:
//   s_prev = #ones in obs[r, 0..t-1];  f_prev = t - s_prev
//   a1 = alpha1+s_prev, b1 = beta1+f_prev, a2 = alpha2+s_prev, b2 = beta2+f_prev
//   d(t) = sum_{u<t} [ log(sel2_u*(AB1+u)) - log(sel1_u*(AB2+u)) ]
//   post_mixweight = w / (w + (1-w)*exp(d))
// Output layout: [5, B, T] = {a1, b1, a2, b2, post_mixweight}
//
// Experiment ledger (kernel-only time = dur_us - ~430us harness fill):
//   R3 block/row 256thr + NT stores ........ ~330us
//   R4 wave/row, zero barriers + NT stores .. ~330us  (sync exonerated)
//   R5 block/row 1024thr, 16x fewer rows in
//      flight, 16KB contiguous bursts + NT .. ~310us  (locality ~exonerated)
// Traffic roofline is ~130us (805 MB @ 6.2 TB/s, the rate the harness fill
// achieves on this same output buffer with PLAIN stores). Compute bound is
// ~25-50us. The one untested invariant across R3/R4/R5 is
// __builtin_nontemporal_store: the nt/no-allocate path plausibly bypasses
// L2 write-combining and feeds HBM small bursts (~2.5 TB/s effective).
// R6 = R5 with the 5 output streams written via PLAIN cached float4 stores
// (thread-contiguous 1KB/wave-inst -> full 64B sectors, no RFO; dirty-L2
// drain at kernel end ~5us). Single-variable experiment vs R5.

#define BLOCK 1024
#define VEC 4
#define NWAVES (BLOCK / 64)   // 16

typedef float v4f __attribute__((ext_vector_type(4)));

__global__ __launch_bounds__(BLOCK, 4) void bbm_kernel(
    const float* __restrict__ obs,
    const float* __restrict__ alpha1, const float* __restrict__ beta1,
    const float* __restrict__ alpha2, const float* __restrict__ beta2,
    const float* __restrict__ mixw,
    float* __restrict__ out,
    int T, size_t bt)
{
    const int row  = blockIdx.x;
    const int tid  = threadIdx.x;
    const int lane = tid & 63;
    const int wid  = tid >> 6;

    __shared__ int   sPart[NWAVES];
    __shared__ float dPart[NWAVES];

    const float A1 = alpha1[row], B1 = beta1[row];
    const float A2 = alpha2[row], B2 = beta2[row];
    const float w  = mixw[0];
    const float AB1 = A1 + B1, AB2 = A2 + B2;
    const float w2 = 1.0f - w;

    const float* __restrict__ orow = obs + (size_t)row * T;
    float* __restrict__ obase = out + (size_t)row * T;

    const unsigned long long lt_mask = ((unsigned long long)1 << lane) - 1ull;

    int   carry_s = 0;
    float carry_d = 0.0f;

    const int EPB  = BLOCK * VEC;       // 4096 elements per block-segment
    const int segs = T / EPB;           // 2 for T=8192

    // preload first segment (thread-contiguous float4 -> 16KB/block burst)
    v4f cur = *(const v4f*)(orow + tid * VEC);

    for (int seg = 0; seg < segs; ++seg) {
        const int t0 = seg * EPB + tid * VEC;

        // ---- bits + thread-local exclusive prefix ----
        int bit[VEC], sloc[VEC];
        int ts = 0;
        #pragma unroll
        for (int j = 0; j < VEC; ++j) { bit[j] = cur[j] > 0.5f; sloc[j] = ts; ts += bit[j]; }

        // ---- wave bit scan via ballot+popc ----
        unsigned long long m0 = __ballot(bit[0]);
        unsigned long long m1 = __ballot(bit[1]);
        unsigned long long m2 = __ballot(bit[2]);
        unsigned long long m3 = __ballot(bit[3]);
        const int wave_excl = __builtin_popcountll(m0 & lt_mask)
                            + __builtin_popcountll(m1 & lt_mask)
                            + __builtin_popcountll(m2 & lt_mask)
                            + __builtin_popcountll(m3 & lt_mask);
        const int wave_tot  = __builtin_popcountll(m0) + __builtin_popcountll(m1)
                            + __builtin_popcountll(m2) + __builtin_popcountll(m3);
        if (lane == 0) sPart[wid] = wave_tot;
        __syncthreads();
        int prior = 0, total = 0;
        #pragma unroll
        for (int wI = 0; wI < NWAVES; ++wI) {
            int p = sPart[wI];
            total += p;
            if (wI < wid) prior += p;
        }
        const int tbase_s = carry_s + prior + wave_excl;

        // ---- per-elem delta + thread-local exclusive prefix ----
        float dloc[VEC];
        float td = 0.0f;
        #pragma unroll
        for (int j = 0; j < VEC; ++j) {
            const float ft = (float)(t0 + j);
            const float fs = (float)(tbase_s + sloc[j]);
            const float fp = ft - fs;
            const float sel1 = bit[j] ? (A1 + fs) : (B1 + fp);
            const float sel2 = bit[j] ? (A2 + fs) : (B2 + fp);
            const float delta = __logf(sel2 * (AB1 + ft)) - __logf(sel1 * (AB2 + ft));
            dloc[j] = td;
            td += delta;
        }

        // ---- wave shuffle-scan over per-thread delta totals ----
        float incl_d = td;
        #pragma unroll
        for (int off = 1; off < 64; off <<= 1) {
            float n = __shfl_up(incl_d, off, 64);
            if (lane >= off) incl_d += n;
        }
        if (lane == 63) dPart[wid] = incl_d;
        __syncthreads();
        float priord = 0.0f, totald = 0.0f;
        #pragma unroll
        for (int wI = 0; wI < NWAVES; ++wI) {
            float p = dPart[wI];
            totald += p;
            if (wI < wid) priord += p;
        }
        const float tbase_d = carry_d + priord + (incl_d - td);

        // ---- prefetch next segment AFTER the barriers (no barrier between
        //      issue and consumption -> full-segment latency cover, no drain)
        v4f nxt;
        if (seg + 1 < segs) nxt = *(const v4f*)(orow + (seg + 1) * EPB + tid * VEC);

        // ---- outputs: one thread-contiguous float4 PLAIN store per stream
        //      (L2 write-combining path, same as the 6.2 TB/s harness fill)
        v4f va1, vb1, va2, vb2, vpm;
        #pragma unroll
        for (int j = 0; j < VEC; ++j) {
            const float ft = (float)(t0 + j);
            const float fs = (float)(tbase_s + sloc[j]);
            const float fp = ft - fs;
            const float d  = tbase_d + dloc[j];
            va1[j] = A1 + fs;
            vb1[j] = B1 + fp;
            va2[j] = A2 + fs;
            vb2[j] = B2 + fp;
            vpm[j] = __fdividef(w, w + w2 * __expf(d));
        }
        float* p = obase + t0;
        *(v4f*)(p)          = va1;
        *(v4f*)(p + bt)     = vb1;
        *(v4f*)(p + 2 * bt) = va2;
        *(v4f*)(p + 3 * bt) = vb2;
        *(v4f*)(p + 4 * bt) = vpm;

        carry_s += total;
        carry_d += totald;
        cur = nxt;
    }
}

extern "C" void kernel_launch(void* const* d_in, const int* in_sizes, int n_in,
                              void* d_out, int out_size, void* d_ws, size_t ws_size,
                              hipStream_t stream) {
    const float* obs    = (const float*)d_in[0];
    const float* alpha1 = (const float*)d_in[1];
    const float* beta1  = (const float*)d_in[2];
    const float* alpha2 = (const float*)d_in[3];
    const float* beta2  = (const float*)d_in[4];
    const float* mixw   = (const float*)d_in[5];

    const int Bn = in_sizes[1];
    const int Tn = in_sizes[0] / Bn;
    const size_t bt = (size_t)Bn * (size_t)Tn;

    bbm_kernel<<<Bn, BLOCK, 0, stream>>>(obs, alpha1, beta1, alpha2, beta2,
                                         mixw, (float*)d_out, Tn, bt);
}